// Round 9
// baseline (406.410 us; speedup 1.0000x reference)
//
#include <hip/hip_runtime.h>
#include <math.h>

#define L 256
#define DP 128
#define NH 4
#define DH 32
#define NROW 65536   /* L*L */

typedef unsigned short ushort_t;
typedef __attribute__((ext_vector_type(8))) short short8;
typedef __attribute__((ext_vector_type(4))) float f32x4;
typedef __attribute__((ext_vector_type(4))) unsigned int u32x4;

constexpr float SCALING = 0.17677669529663687f;  /* 1/sqrt(32) */

static __device__ __forceinline__ unsigned short f2bf(float f) {
    unsigned u = __builtin_bit_cast(unsigned, f);
    u = u + 0x7fffu + ((u >> 16) & 1u);
    return (unsigned short)(u >> 16);
}
static __device__ __forceinline__ float bf2f(unsigned short h) {
    unsigned u = ((unsigned)h) << 16;
    return __builtin_bit_cast(float, u);
}
static __device__ __forceinline__ unsigned packbf(float lo, float hi) {
    return ((unsigned)f2bf(hi) << 16) | (unsigned)f2bf(lo);
}

// ---------------- prep: transpose/convert weights ----------------
__global__ __launch_bounds__(256) void prep_kernel(
    const float* __restrict__ Wq, const float* __restrict__ Wk, const float* __restrict__ Wv,
    const float* __restrict__ Wb, const float* __restrict__ Wg, const float* __restrict__ Wo,
    ushort_t* __restrict__ WtAll, ushort_t* __restrict__ WohT, ushort_t* __restrict__ WolT)
{
    int rowi = blockIdx.x * 16 + (threadIdx.x >> 4);
    int d0 = (threadIdx.x & 15) * 8;
    #pragma unroll
    for (int dd = 0; dd < 8; ++dd) {
        int d = d0 + dd;
        if (rowi < 512) {
            int n = rowi & 127;
            float val;
            if (rowi < 128)      val = Wq[d * 128 + n] * SCALING;
            else if (rowi < 256) val = Wk[d * 128 + n];
            else if (rowi < 384) val = Wv[d * 128 + n];
            else                 val = Wg[d * 128 + n];
            WtAll[rowi * 128 + d] = f2bf(val);
        } else if (rowi < 516) {
            WtAll[rowi * 128 + d] = f2bf(Wb[d * 4 + (rowi - 512)]);
        } else if (rowi < 528) {
            WtAll[rowi * 128 + d] = 0;
        } else if (rowi < 656) {
            int n = rowi - 528;
            WohT[n * 128 + d] = f2bf(Wo[d * 128 + n]);
        } else {
            int n = rowi - 656;
            float wv = Wo[d * 128 + n];
            unsigned short hb = f2bf(wv);
            WolT[n * 128 + d] = f2bf(wv - bf2f(hb));
        }
    }
}

// ---------------- Kernel A: LayerNorm + MFMA projections ----------------
// 32 rows/block (grid 2048 -> 8 blocks/CU). A-frags hoisted to registers.
__global__ __launch_bounds__(256, 8) void ln_proj_mfma(
    const float* __restrict__ pair, const float* __restrict__ gamma, const float* __restrict__ beta,
    const ushort_t* __restrict__ WtAll, const float* __restrict__ bgv,
    ushort_t* __restrict__ qo, ushort_t* __restrict__ ko, ushort_t* __restrict__ vo,
    ushort_t* __restrict__ gateo, float* __restrict__ biasT)
{
    __shared__ __align__(16) unsigned char xs[32 * 256];   // [32 rows][128 bf16], swizzled

    const int t = threadIdx.x;
    const int w = t >> 6, lane = t & 63;
    const int c = lane & 15, g = lane >> 4;
    const int base = blockIdx.x * 32;

    // ---- LN (fp32) -> xs bf16 : wave w handles rows w*8 .. w*8+7 ----
    {
        const float* pr = pair + ((size_t)base + w * 8) * DP;
        float e0[8], e1[8];
        #pragma unroll
        for (int r = 0; r < 8; ++r) {
            e0[r] = pr[r * DP + lane];
            e1[r] = pr[r * DP + 64 + lane];
        }
        const float g0 = gamma[lane], g1 = gamma[lane + 64];
        const float b0 = beta[lane],  b1 = beta[lane + 64];
        #pragma unroll
        for (int r = 0; r < 8; ++r) {
            float s = e0[r] + e1[r], ss = e0[r] * e0[r] + e1[r] * e1[r];
            #pragma unroll
            for (int o = 32; o > 0; o >>= 1) { s += __shfl_xor(s, o); ss += __shfl_xor(ss, o); }
            float mu = s * (1.f / DP);
            float rq = rsqrtf(ss * (1.f / DP) - mu * mu + 1e-5f);
            int rl = w * 8 + r;
            unsigned swz = (unsigned)((rl & 7) << 4);
            *(ushort_t*)(xs + (((unsigned)(rl * 256 + 2 * lane)) ^ swz)) = f2bf((e0[r] - mu) * rq * g0 + b0);
            *(ushort_t*)(xs + (((unsigned)(rl * 256 + 2 * (lane + 64))) ^ swz)) = f2bf((e1[r] - mu) * rq * g1 + b1);
        }
    }
    __syncthreads();

    // ---- hoist A-fragments (2 row-groups) ----
    short8 af[2][4];
    #pragma unroll
    for (int rg = 0; rg < 2; ++rg) {
        const int rl = rg * 16 + c;
        const unsigned swz = (unsigned)((rl & 7) << 4);
        #pragma unroll
        for (int kk = 0; kk < 4; ++kk)
            af[rg][kk] = *(const short8*)(xs + (((unsigned)(rl * 256 + kk * 64 + g * 16)) ^ swz));
    }

    // ---- GEMM: wave w owns n-tiles {w, w+4, ..., w+28}; wave 3 also tile 32 ----
    const int mtot = (w == 3) ? 9 : 8;
    for (int m = 0; m < mtot; ++m) {
        const int nt = (m < 8) ? (w + 4 * m) : 32;
        const ushort_t* wbp = WtAll + (size_t)(nt * 16 + c) * 128 + 8 * g;
        short8 bw[4];
        #pragma unroll
        for (int kk = 0; kk < 4; ++kk) bw[kk] = *(const short8*)(wbp + kk * 32);

        const int n = nt * 16 + c;
        #pragma unroll
        for (int rg = 0; rg < 2; ++rg) {
            f32x4 acc = {0.f, 0.f, 0.f, 0.f};
            #pragma unroll
            for (int kk = 0; kk < 4; ++kk)
                acc = __builtin_amdgcn_mfma_f32_16x16x32_bf16(af[rg][kk], bw[kk], acc, 0, 0, 0);

            const int rowb = base + rg * 16 + 4 * g;
            if (nt < 8) {
                #pragma unroll
                for (int e = 0; e < 4; ++e) qo[(size_t)(rowb + e) * 128 + n] = f2bf(acc[e]);
            } else if (nt < 16) {
                #pragma unroll
                for (int e = 0; e < 4; ++e) ko[(size_t)(rowb + e) * 128 + (n - 128)] = f2bf(acc[e]);
            } else if (nt < 24) {
                #pragma unroll
                for (int e = 0; e < 4; ++e) vo[(size_t)(rowb + e) * 128 + (n - 256)] = f2bf(acc[e]);
            } else if (nt < 32) {
                float bgn = bgv[n - 384];
                #pragma unroll
                for (int e = 0; e < 4; ++e)
                    gateo[(size_t)(rowb + e) * 128 + (n - 384)] =
                        f2bf(1.f / (1.f + __expf(-(acc[e] + bgn))));
            } else {
                if (c < 4) {
                    #pragma unroll
                    for (int e = 0; e < 4; ++e)
                        biasT[(size_t)c * NROW + rowb + e] = acc[e];
                }
            }
        }
    }
}

// ---------------- Kernel B: swapped-operand MFMA attention + gate fusion ----------------
// 512 threads (8 waves x 32 j-rows). S^T = K Q^T; P^T packed in-register as PV
// B-operand; O^T = V^T P^T. Epilogue: x = gate .* (O*inv) hi/lo bf16.
__global__ __launch_bounds__(512, 8) void attn_mfma(
    const ushort_t* __restrict__ qbf, const ushort_t* __restrict__ kbf, const ushort_t* __restrict__ vbf,
    const ushort_t* __restrict__ gbf, const float* __restrict__ biasT,
    ushort_t* __restrict__ xh, ushort_t* __restrict__ xl)
{
    __shared__ __align__(16) unsigned char Kb[256 * 64];     // [256 k][32 bf16], linear
    __shared__ __align__(16) unsigned char Vt[32 * 512];     // [32 d][256 bf16 k-perm], XOR swizzled

    const int h = blockIdx.x & 3, i = blockIdx.x >> 2;
    const int t = threadIdx.x, w = t >> 6, lane = t & 63;
    const int c = lane & 15, g = lane >> 4;

    // ---- Q fragments first (global latency overlaps staging) ----
    const int j0 = w * 32;
    short8 qf[2];
    {
        const ushort_t* qg = qbf + (size_t)(i * 256 + j0) * 128 + h * 32;
        #pragma unroll
        for (int jt = 0; jt < 2; ++jt)
            qf[jt] = *(const short8*)(qg + (size_t)(jt * 16 + c) * 128 + 8 * g);
    }

    // ---- stage K (16B loads, linear row-major) ----
    {
        const ushort_t* kg = kbf + (size_t)(i * 256) * 128 + h * 32;
        #pragma unroll
        for (int it = 0; it < 2; ++it) {
            int idx = it * 512 + t;          // 0..1023 16B-units
            int kr = idx >> 2, dp4 = idx & 3;
            *(u32x4*)(Kb + kr * 64 + dp4 * 16) = *(const u32x4*)(kg + (size_t)kr * 128 + dp4 * 8);
        }
    }
    // ---- stage V transposed, k-permuted: pos p=g*8+q holds k=(q<4)?4g+q:16+4g+(q-4) ----
    {
        const ushort_t* vg = vbf + (size_t)(i * 256) * 128 + h * 32;
        #pragma unroll
        for (int it = 0; it < 2; ++it) {
            int idx = it * 512 + t;
            int kp = idx >> 3, dp = idx & 7;
            int kt = kp >> 4, cc = kp & 15;
            int a = cc & 3, gg = cc >> 2;
            int k1 = (a < 2) ? (4 * gg + 2 * a) : (12 + 4 * gg + 2 * a);
            int r0 = kt * 32 + k1;
            uint2 va = *(const uint2*)(vg + (size_t)r0 * 128 + dp * 4);
            uint2 vb = *(const uint2*)(vg + (size_t)(r0 + 1) * 128 + dp * 4);
            unsigned av[4] = { va.x & 0xffffu, va.x >> 16, va.y & 0xffffu, va.y >> 16 };
            unsigned bv[4] = { vb.x & 0xffffu, vb.x >> 16, vb.y & 0xffffu, vb.y >> 16 };
            int kcolb = kt * 64 + 4 * cc;
            #pragma unroll
            for (int dd = 0; dd < 4; ++dd) {
                int d = 4 * dp + dd;
                unsigned pk = (bv[dd] << 16) | av[dd];
                *(unsigned*)(Vt + (((unsigned)(d * 512 + kcolb)) ^ ((unsigned)((d & 7) << 4)))) = pk;
            }
        }
    }
    __syncthreads();

    const float* biasH = biasT + (size_t)h * NROW;

    f32x4 O[2][2];
    float rsum[2] = {0.f, 0.f};
    #pragma unroll
    for (int jt = 0; jt < 2; ++jt) {
        O[jt][0] = (f32x4){0.f, 0.f, 0.f, 0.f};
        O[jt][1] = (f32x4){0.f, 0.f, 0.f, 0.f};
    }

    for (int kt = 0; kt < 8; ++kt) {
        short8 kf[2];
        #pragma unroll
        for (int ks = 0; ks < 2; ++ks)
            kf[ks] = *(const short8*)(Kb + (kt * 32 + ks * 16 + c) * 64 + g * 16);
        short8 vb0 = *(const short8*)(Vt + (((unsigned)(c * 512 + kt * 64 + g * 16)) ^ ((unsigned)((c & 7) << 4))));
        short8 vb1 = *(const short8*)(Vt + (((unsigned)((16 + c) * 512 + kt * 64 + g * 16)) ^ ((unsigned)(((16 + c) & 7) << 4))));

        #pragma unroll
        for (int jt = 0; jt < 2; ++jt) {
            f32x4 s0, s1;
            {
                f32x4 z = {0.f, 0.f, 0.f, 0.f};
                s0 = __builtin_amdgcn_mfma_f32_16x16x32_bf16(kf[0], qf[jt], z, 0, 0, 0);
                s1 = __builtin_amdgcn_mfma_f32_16x16x32_bf16(kf[1], qf[jt], z, 0, 0, 0);
            }
            const int jrow = j0 + jt * 16 + c;
            const f32x4 b0 = *(const f32x4*)(biasH + (size_t)jrow * 256 + kt * 32 + 4 * g);
            const f32x4 b1 = *(const f32x4*)(biasH + (size_t)jrow * 256 + kt * 32 + 16 + 4 * g);
            #pragma unroll
            for (int e = 0; e < 4; ++e) {
                s0[e] = __expf(s0[e] + b0[e]);
                s1[e] = __expf(s1[e] + b1[e]);
            }
            rsum[jt] += (s0[0] + s0[1] + s0[2] + s0[3]) + (s1[0] + s1[1] + s1[2] + s1[3]);
            u32x4 pk;
            pk[0] = packbf(s0[0], s0[1]);
            pk[1] = packbf(s0[2], s0[3]);
            pk[2] = packbf(s1[0], s1[1]);
            pk[3] = packbf(s1[2], s1[3]);
            short8 pa = __builtin_bit_cast(short8, pk);
            O[jt][0] = __builtin_amdgcn_mfma_f32_16x16x32_bf16(vb0, pa, O[jt][0], 0, 0, 0);
            O[jt][1] = __builtin_amdgcn_mfma_f32_16x16x32_bf16(vb1, pa, O[jt][1], 0, 0, 0);
        }
    }

    // rowsum over g-groups
    #pragma unroll
    for (int jt = 0; jt < 2; ++jt) {
        float v = rsum[jt];
        v += __shfl_xor(v, 16);
        v += __shfl_xor(v, 32);
        rsum[jt] = 1.f / v;
    }
    // epilogue: x = gate .* (O*inv), hi/lo bf16, store
    const ushort_t* gB = gbf + (size_t)(i * 256 + j0) * 128 + h * 32;
    ushort_t* xhB = xh + (size_t)(i * 256 + j0) * 128 + h * 32;
    ushort_t* xlB = xl + (size_t)(i * 256 + j0) * 128 + h * 32;
    #pragma unroll
    for (int jt = 0; jt < 2; ++jt) {
        const float inv = rsum[jt];
        #pragma unroll
        for (int dt = 0; dt < 2; ++dt) {
            const int off = (jt * 16 + c) * 128 + dt * 16 + 4 * g;
            uint2 gv = *(const uint2*)(gB + off);
            unsigned gs[4] = { gv.x & 0xffffu, gv.x >> 16, gv.y & 0xffffu, gv.y >> 16 };
            float xq[4];
            unsigned short hq[4];
            #pragma unroll
            for (int e = 0; e < 4; ++e) {
                xq[e] = bf2f((unsigned short)gs[e]) * O[jt][dt][e] * inv;
                hq[e] = f2bf(xq[e]);
            }
            uint2 hv, lv;
            hv.x = ((unsigned)hq[1] << 16) | hq[0];
            hv.y = ((unsigned)hq[3] << 16) | hq[2];
            lv.x = packbf(xq[0] - bf2f(hq[0]), xq[1] - bf2f(hq[1]));
            lv.y = packbf(xq[2] - bf2f(hq[2]), xq[3] - bf2f(hq[3]));
            *(uint2*)(xhB + off) = hv;
            *(uint2*)(xlB + off) = lv;
        }
    }
}

// ---------------- Kernel C: out = x @ Wo + bo, x = xh+xl bf16 pair ----------------
// grid 2048: block = (64 rows, 4 n-tiles). 8192 waves total.
__global__ __launch_bounds__(256, 8) void out_proj_mfma(
    const ushort_t* __restrict__ xh, const ushort_t* __restrict__ xl,
    const ushort_t* __restrict__ WohT, const ushort_t* __restrict__ WolT,
    const float* __restrict__ bo, float* __restrict__ out)
{
    const int t = threadIdx.x;
    const int w = t >> 6, lane = t & 63;
    const int c = lane & 15, g = lane >> 4;
    const int base = (blockIdx.x >> 1) * 64;
    const int nh = blockIdx.x & 1;

    const size_t arow = (size_t)(base + w * 16 + c) * 128;
    short8 ah[4], al[4];
    #pragma unroll
    for (int kk = 0; kk < 4; ++kk) {
        ah[kk] = *(const short8*)(xh + arow + kk * 32 + g * 8);
        al[kk] = *(const short8*)(xl + arow + kk * 32 + g * 8);
    }

    const int rowb = base + w * 16 + 4 * g;
    #pragma unroll
    for (int m = 0; m < 4; ++m) {
        const int nt = nh * 4 + m;
        f32x4 acc = {0.f, 0.f, 0.f, 0.f};
        const ushort_t* wh = WohT + (size_t)(nt * 16 + c) * 128 + 8 * g;
        const ushort_t* wl = WolT + (size_t)(nt * 16 + c) * 128 + 8 * g;
        #pragma unroll
        for (int kk = 0; kk < 4; ++kk) {
            short8 bh = *(const short8*)(wh + kk * 32);
            short8 bl = *(const short8*)(wl + kk * 32);
            acc = __builtin_amdgcn_mfma_f32_16x16x32_bf16(ah[kk], bh, acc, 0, 0, 0);
            acc = __builtin_amdgcn_mfma_f32_16x16x32_bf16(ah[kk], bl, acc, 0, 0, 0);
            acc = __builtin_amdgcn_mfma_f32_16x16x32_bf16(al[kk], bh, acc, 0, 0, 0);
        }
        int n = nt * 16 + c;
        float bon = bo[n];
        #pragma unroll
        for (int e = 0; e < 4; ++e)
            out[(size_t)(rowb + e) * 128 + n] = acc[e] + bon;
    }
}

extern "C" void kernel_launch(void* const* d_in, const int* in_sizes, int n_in,
                              void* d_out, int out_size, void* d_ws, size_t ws_size,
                              hipStream_t stream) {
    const float* pair  = (const float*)d_in[0];
    const float* gamma = (const float*)d_in[1];
    const float* beta  = (const float*)d_in[2];
    const float* Wq    = (const float*)d_in[3];
    const float* Wk    = (const float*)d_in[4];
    const float* Wv    = (const float*)d_in[5];
    const float* Wb    = (const float*)d_in[6];
    const float* Wg    = (const float*)d_in[7];
    const float* bg    = (const float*)d_in[8];
    const float* Wo    = (const float*)d_in[9];
    const float* bo    = (const float*)d_in[10];

    unsigned char* ws = (unsigned char*)d_ws;
    size_t off = 0;
    ushort_t* q_bf   = (ushort_t*)(ws + off); off += (size_t)NROW * 128 * 2;
    ushort_t* k_bf   = (ushort_t*)(ws + off); off += (size_t)NROW * 128 * 2;
    ushort_t* v_bf   = (ushort_t*)(ws + off); off += (size_t)NROW * 128 * 2;
    ushort_t* g_bf   = (ushort_t*)(ws + off); off += (size_t)NROW * 128 * 2;
    ushort_t* xh_bf  = (ushort_t*)(ws + off); off += (size_t)NROW * 128 * 2;
    ushort_t* xl_bf  = (ushort_t*)(ws + off); off += (size_t)NROW * 128 * 2;
    float*    biasT  = (float*)(ws + off);    off += (size_t)NH * NROW * 4;
    ushort_t* WtAll  = (ushort_t*)(ws + off); off += 528 * 128 * 2;
    ushort_t* WohT   = (ushort_t*)(ws + off); off += 128 * 128 * 2;
    ushort_t* WolT   = (ushort_t*)(ws + off); off += 128 * 128 * 2;

    prep_kernel<<<49, 256, 0, stream>>>(Wq, Wk, Wv, Wb, Wg, Wo, WtAll, WohT, WolT);
    ln_proj_mfma<<<NROW / 32, 256, 0, stream>>>(pair, gamma, beta, WtAll, bg,
                                                q_bf, k_bf, v_bf, g_bf, biasT);
    attn_mfma<<<L * NH, 512, 0, stream>>>(q_bf, k_bf, v_bf, g_bf, biasT, xh_bf, xl_bf);
    out_proj_mfma<<<NROW / 32, 256, 0, stream>>>(xh_bf, xl_bf, WohT, WolT, bo, (float*)d_out);
}

// Round 10
// 229.520 us; speedup vs baseline: 1.7707x; 1.7707x over previous
//
#include <hip/hip_runtime.h>
#include <math.h>

#define L 256
#define DP 128
#define NH 4
#define DH 32
#define NROW 65536   /* L*L */

typedef unsigned short ushort_t;
typedef __attribute__((ext_vector_type(8))) short short8;
typedef __attribute__((ext_vector_type(4))) float f32x4;
typedef __attribute__((ext_vector_type(4))) unsigned int u32x4;

constexpr float SCALING = 0.17677669529663687f;  /* 1/sqrt(32) */

static __device__ __forceinline__ unsigned short f2bf(float f) {
    unsigned u = __builtin_bit_cast(unsigned, f);
    u = u + 0x7fffu + ((u >> 16) & 1u);
    return (unsigned short)(u >> 16);
}
static __device__ __forceinline__ float bf2f(unsigned short h) {
    unsigned u = ((unsigned)h) << 16;
    return __builtin_bit_cast(float, u);
}
static __device__ __forceinline__ unsigned packbf(float lo, float hi) {
    return ((unsigned)f2bf(hi) << 16) | (unsigned)f2bf(lo);
}

// ---------------- prep: transpose/convert weights ----------------
__global__ __launch_bounds__(256) void prep_kernel(
    const float* __restrict__ Wq, const float* __restrict__ Wk, const float* __restrict__ Wv,
    const float* __restrict__ Wb, const float* __restrict__ Wg, const float* __restrict__ Wo,
    ushort_t* __restrict__ WtAll, ushort_t* __restrict__ WohT, ushort_t* __restrict__ WolT)
{
    int rowi = blockIdx.x * 16 + (threadIdx.x >> 4);
    int d0 = (threadIdx.x & 15) * 8;
    #pragma unroll
    for (int dd = 0; dd < 8; ++dd) {
        int d = d0 + dd;
        if (rowi < 512) {
            int n = rowi & 127;
            float val;
            if (rowi < 128)      val = Wq[d * 128 + n] * SCALING;
            else if (rowi < 256) val = Wk[d * 128 + n];
            else if (rowi < 384) val = Wv[d * 128 + n];
            else                 val = Wg[d * 128 + n];
            WtAll[rowi * 128 + d] = f2bf(val);
        } else if (rowi < 516) {
            WtAll[rowi * 128 + d] = f2bf(Wb[d * 4 + (rowi - 512)]);
        } else if (rowi < 528) {
            WtAll[rowi * 128 + d] = 0;
        } else if (rowi < 656) {
            int n = rowi - 528;
            WohT[n * 128 + d] = f2bf(Wo[d * 128 + n]);
        } else {
            int n = rowi - 656;
            float wv = Wo[d * 128 + n];
            unsigned short hb = f2bf(wv);
            WolT[n * 128 + d] = f2bf(wv - bf2f(hb));
        }
    }
}

// ---------------- Kernel A: LayerNorm + MFMA projections ----------------
// 32 rows/block (grid 2048). Natural VGPR allocation (no min-wave cap).
__global__ __launch_bounds__(256) void ln_proj_mfma(
    const float* __restrict__ pair, const float* __restrict__ gamma, const float* __restrict__ beta,
    const ushort_t* __restrict__ WtAll, const float* __restrict__ bgv,
    ushort_t* __restrict__ qo, ushort_t* __restrict__ ko, ushort_t* __restrict__ vo,
    ushort_t* __restrict__ gateo, float* __restrict__ biasT)
{
    __shared__ __align__(16) unsigned char xs[32 * 256];   // [32 rows][128 bf16], swizzled

    const int t = threadIdx.x;
    const int w = t >> 6, lane = t & 63;
    const int c = lane & 15, g = lane >> 4;
    const int base = blockIdx.x * 32;

    // ---- LN (fp32) -> xs bf16 : wave w handles rows w*8 .. w*8+7 ----
    {
        const float* pr = pair + ((size_t)base + w * 8) * DP;
        float e0[8], e1[8];
        #pragma unroll
        for (int r = 0; r < 8; ++r) {
            e0[r] = pr[r * DP + lane];
            e1[r] = pr[r * DP + 64 + lane];
        }
        const float g0 = gamma[lane], g1 = gamma[lane + 64];
        const float b0 = beta[lane],  b1 = beta[lane + 64];
        #pragma unroll
        for (int r = 0; r < 8; ++r) {
            float s = e0[r] + e1[r], ss = e0[r] * e0[r] + e1[r] * e1[r];
            #pragma unroll
            for (int o = 32; o > 0; o >>= 1) { s += __shfl_xor(s, o); ss += __shfl_xor(ss, o); }
            float mu = s * (1.f / DP);
            float rq = rsqrtf(ss * (1.f / DP) - mu * mu + 1e-5f);
            int rl = w * 8 + r;
            unsigned swz = (unsigned)((rl & 7) << 4);
            *(ushort_t*)(xs + (((unsigned)(rl * 256 + 2 * lane)) ^ swz)) = f2bf((e0[r] - mu) * rq * g0 + b0);
            *(ushort_t*)(xs + (((unsigned)(rl * 256 + 2 * (lane + 64))) ^ swz)) = f2bf((e1[r] - mu) * rq * g1 + b1);
        }
    }
    __syncthreads();

    // ---- hoist A-fragments (2 row-groups) ----
    short8 af[2][4];
    #pragma unroll
    for (int rg = 0; rg < 2; ++rg) {
        const int rl = rg * 16 + c;
        const unsigned swz = (unsigned)((rl & 7) << 4);
        #pragma unroll
        for (int kk = 0; kk < 4; ++kk)
            af[rg][kk] = *(const short8*)(xs + (((unsigned)(rl * 256 + kk * 64 + g * 16)) ^ swz));
    }

    // ---- GEMM: wave w owns n-tiles {w, w+4, ..., w+28}; wave 3 also tile 32 ----
    const int mtot = (w == 3) ? 9 : 8;
    for (int m = 0; m < mtot; ++m) {
        const int nt = (m < 8) ? (w + 4 * m) : 32;
        const ushort_t* wbp = WtAll + (size_t)(nt * 16 + c) * 128 + 8 * g;
        short8 bw[4];
        #pragma unroll
        for (int kk = 0; kk < 4; ++kk) bw[kk] = *(const short8*)(wbp + kk * 32);

        const int n = nt * 16 + c;
        #pragma unroll
        for (int rg = 0; rg < 2; ++rg) {
            f32x4 acc = {0.f, 0.f, 0.f, 0.f};
            #pragma unroll
            for (int kk = 0; kk < 4; ++kk)
                acc = __builtin_amdgcn_mfma_f32_16x16x32_bf16(af[rg][kk], bw[kk], acc, 0, 0, 0);

            const int rowb = base + rg * 16 + 4 * g;
            if (nt < 8) {
                #pragma unroll
                for (int e = 0; e < 4; ++e) qo[(size_t)(rowb + e) * 128 + n] = f2bf(acc[e]);
            } else if (nt < 16) {
                #pragma unroll
                for (int e = 0; e < 4; ++e) ko[(size_t)(rowb + e) * 128 + (n - 128)] = f2bf(acc[e]);
            } else if (nt < 24) {
                #pragma unroll
                for (int e = 0; e < 4; ++e) vo[(size_t)(rowb + e) * 128 + (n - 256)] = f2bf(acc[e]);
            } else if (nt < 32) {
                float bgn = bgv[n - 384];
                #pragma unroll
                for (int e = 0; e < 4; ++e)
                    gateo[(size_t)(rowb + e) * 128 + (n - 384)] =
                        f2bf(1.f / (1.f + __expf(-(acc[e] + bgn))));
            } else {
                if (c < 4) {
                    #pragma unroll
                    for (int e = 0; e < 4; ++e)
                        biasT[(size_t)c * NROW + rowb + e] = acc[e];
                }
            }
        }
    }
}

// ---------------- Kernel B: swapped-operand MFMA attention + gate fusion ----------------
// 512 threads (8 waves x 32 j-rows). Natural VGPR (no min-wave cap — round 9's
// (512,8) forced VGPR=32 and spilled 470 MB/dispatch to scratch).
__global__ __launch_bounds__(512) void attn_mfma(
    const ushort_t* __restrict__ qbf, const ushort_t* __restrict__ kbf, const ushort_t* __restrict__ vbf,
    const ushort_t* __restrict__ gbf, const float* __restrict__ biasT,
    ushort_t* __restrict__ xh, ushort_t* __restrict__ xl)
{
    __shared__ __align__(16) unsigned char Kb[256 * 64];     // [256 k][32 bf16], linear
    __shared__ __align__(16) unsigned char Vt[32 * 512];     // [32 d][256 bf16 k-perm], XOR swizzled

    const int h = blockIdx.x & 3, i = blockIdx.x >> 2;
    const int t = threadIdx.x, w = t >> 6, lane = t & 63;
    const int c = lane & 15, g = lane >> 4;

    // ---- Q fragments first (global latency overlaps staging) ----
    const int j0 = w * 32;
    short8 qf[2];
    {
        const ushort_t* qg = qbf + (size_t)(i * 256 + j0) * 128 + h * 32;
        #pragma unroll
        for (int jt = 0; jt < 2; ++jt)
            qf[jt] = *(const short8*)(qg + (size_t)(jt * 16 + c) * 128 + 8 * g);
    }

    // ---- stage K (16B loads, linear row-major) ----
    {
        const ushort_t* kg = kbf + (size_t)(i * 256) * 128 + h * 32;
        #pragma unroll
        for (int it = 0; it < 2; ++it) {
            int idx = it * 512 + t;          // 0..1023 16B-units
            int kr = idx >> 2, dp4 = idx & 3;
            *(u32x4*)(Kb + kr * 64 + dp4 * 16) = *(const u32x4*)(kg + (size_t)kr * 128 + dp4 * 8);
        }
    }
    // ---- stage V transposed, k-permuted: pos p=g*8+q holds k=(q<4)?4g+q:16+4g+(q-4) ----
    {
        const ushort_t* vg = vbf + (size_t)(i * 256) * 128 + h * 32;
        #pragma unroll
        for (int it = 0; it < 2; ++it) {
            int idx = it * 512 + t;
            int kp = idx >> 3, dp = idx & 7;
            int kt = kp >> 4, cc = kp & 15;
            int a = cc & 3, gg = cc >> 2;
            int k1 = (a < 2) ? (4 * gg + 2 * a) : (12 + 4 * gg + 2 * a);
            int r0 = kt * 32 + k1;
            uint2 va = *(const uint2*)(vg + (size_t)r0 * 128 + dp * 4);
            uint2 vb = *(const uint2*)(vg + (size_t)(r0 + 1) * 128 + dp * 4);
            unsigned av[4] = { va.x & 0xffffu, va.x >> 16, va.y & 0xffffu, va.y >> 16 };
            unsigned bv[4] = { vb.x & 0xffffu, vb.x >> 16, vb.y & 0xffffu, vb.y >> 16 };
            int kcolb = kt * 64 + 4 * cc;
            #pragma unroll
            for (int dd = 0; dd < 4; ++dd) {
                int d = 4 * dp + dd;
                unsigned pk = (bv[dd] << 16) | av[dd];
                *(unsigned*)(Vt + (((unsigned)(d * 512 + kcolb)) ^ ((unsigned)((d & 7) << 4)))) = pk;
            }
        }
    }
    __syncthreads();

    const float* biasH = biasT + (size_t)h * NROW;

    f32x4 O[2][2];
    float rsum[2] = {0.f, 0.f};
    #pragma unroll
    for (int jt = 0; jt < 2; ++jt) {
        O[jt][0] = (f32x4){0.f, 0.f, 0.f, 0.f};
        O[jt][1] = (f32x4){0.f, 0.f, 0.f, 0.f};
    }

    for (int kt = 0; kt < 8; ++kt) {
        short8 kf[2];
        #pragma unroll
        for (int ks = 0; ks < 2; ++ks)
            kf[ks] = *(const short8*)(Kb + (kt * 32 + ks * 16 + c) * 64 + g * 16);
        short8 vb0 = *(const short8*)(Vt + (((unsigned)(c * 512 + kt * 64 + g * 16)) ^ ((unsigned)((c & 7) << 4))));
        short8 vb1 = *(const short8*)(Vt + (((unsigned)((16 + c) * 512 + kt * 64 + g * 16)) ^ ((unsigned)(((16 + c) & 7) << 4))));

        #pragma unroll
        for (int jt = 0; jt < 2; ++jt) {
            f32x4 s0, s1;
            {
                f32x4 z = {0.f, 0.f, 0.f, 0.f};
                s0 = __builtin_amdgcn_mfma_f32_16x16x32_bf16(kf[0], qf[jt], z, 0, 0, 0);
                s1 = __builtin_amdgcn_mfma_f32_16x16x32_bf16(kf[1], qf[jt], z, 0, 0, 0);
            }
            const int jrow = j0 + jt * 16 + c;
            const f32x4 b0 = *(const f32x4*)(biasH + (size_t)jrow * 256 + kt * 32 + 4 * g);
            const f32x4 b1 = *(const f32x4*)(biasH + (size_t)jrow * 256 + kt * 32 + 16 + 4 * g);
            #pragma unroll
            for (int e = 0; e < 4; ++e) {
                s0[e] = __expf(s0[e] + b0[e]);
                s1[e] = __expf(s1[e] + b1[e]);
            }
            rsum[jt] += (s0[0] + s0[1] + s0[2] + s0[3]) + (s1[0] + s1[1] + s1[2] + s1[3]);
            u32x4 pk;
            pk[0] = packbf(s0[0], s0[1]);
            pk[1] = packbf(s0[2], s0[3]);
            pk[2] = packbf(s1[0], s1[1]);
            pk[3] = packbf(s1[2], s1[3]);
            short8 pa = __builtin_bit_cast(short8, pk);
            O[jt][0] = __builtin_amdgcn_mfma_f32_16x16x32_bf16(vb0, pa, O[jt][0], 0, 0, 0);
            O[jt][1] = __builtin_amdgcn_mfma_f32_16x16x32_bf16(vb1, pa, O[jt][1], 0, 0, 0);
        }
    }

    // rowsum over g-groups
    #pragma unroll
    for (int jt = 0; jt < 2; ++jt) {
        float v = rsum[jt];
        v += __shfl_xor(v, 16);
        v += __shfl_xor(v, 32);
        rsum[jt] = 1.f / v;
    }
    // epilogue: x = gate .* (O*inv), hi/lo bf16, store
    const ushort_t* gB = gbf + (size_t)(i * 256 + j0) * 128 + h * 32;
    ushort_t* xhB = xh + (size_t)(i * 256 + j0) * 128 + h * 32;
    ushort_t* xlB = xl + (size_t)(i * 256 + j0) * 128 + h * 32;
    #pragma unroll
    for (int jt = 0; jt < 2; ++jt) {
        const float inv = rsum[jt];
        #pragma unroll
        for (int dt = 0; dt < 2; ++dt) {
            const int off = (jt * 16 + c) * 128 + dt * 16 + 4 * g;
            uint2 gv = *(const uint2*)(gB + off);
            unsigned gs[4] = { gv.x & 0xffffu, gv.x >> 16, gv.y & 0xffffu, gv.y >> 16 };
            float xq[4];
            unsigned short hq[4];
            #pragma unroll
            for (int e = 0; e < 4; ++e) {
                xq[e] = bf2f((unsigned short)gs[e]) * O[jt][dt][e] * inv;
                hq[e] = f2bf(xq[e]);
            }
            uint2 hv, lv;
            hv.x = ((unsigned)hq[1] << 16) | hq[0];
            hv.y = ((unsigned)hq[3] << 16) | hq[2];
            lv.x = packbf(xq[0] - bf2f(hq[0]), xq[1] - bf2f(hq[1]));
            lv.y = packbf(xq[2] - bf2f(hq[2]), xq[3] - bf2f(hq[3]));
            *(uint2*)(xhB + off) = hv;
            *(uint2*)(xlB + off) = lv;
        }
    }
}

// ---------------- Kernel C: out = x @ Wo + bo, x = xh+xl bf16 pair ----------------
// grid 2048: block = (64 rows, 4 n-tiles).
__global__ __launch_bounds__(256) void out_proj_mfma(
    const ushort_t* __restrict__ xh, const ushort_t* __restrict__ xl,
    const ushort_t* __restrict__ WohT, const ushort_t* __restrict__ WolT,
    const float* __restrict__ bo, float* __restrict__ out)
{
    const int t = threadIdx.x;
    const int w = t >> 6, lane = t & 63;
    const int c = lane & 15, g = lane >> 4;
    const int base = (blockIdx.x >> 1) * 64;
    const int nh = blockIdx.x & 1;

    const size_t arow = (size_t)(base + w * 16 + c) * 128;
    short8 ah[4], al[4];
    #pragma unroll
    for (int kk = 0; kk < 4; ++kk) {
        ah[kk] = *(const short8*)(xh + arow + kk * 32 + g * 8);
        al[kk] = *(const short8*)(xl + arow + kk * 32 + g * 8);
    }

    const int rowb = base + w * 16 + 4 * g;
    #pragma unroll
    for (int m = 0; m < 4; ++m) {
        const int nt = nh * 4 + m;
        f32x4 acc = {0.f, 0.f, 0.f, 0.f};
        const ushort_t* wh = WohT + (size_t)(nt * 16 + c) * 128 + 8 * g;
        const ushort_t* wl = WolT + (size_t)(nt * 16 + c) * 128 + 8 * g;
        #pragma unroll
        for (int kk = 0; kk < 4; ++kk) {
            short8 bh = *(const short8*)(wh + kk * 32);
            short8 bl = *(const short8*)(wl + kk * 32);
            acc = __builtin_amdgcn_mfma_f32_16x16x32_bf16(ah[kk], bh, acc, 0, 0, 0);
            acc = __builtin_amdgcn_mfma_f32_16x16x32_bf16(ah[kk], bl, acc, 0, 0, 0);
            acc = __builtin_amdgcn_mfma_f32_16x16x32_bf16(al[kk], bh, acc, 0, 0, 0);
        }
        int n = nt * 16 + c;
        float bon = bo[n];
        #pragma unroll
        for (int e = 0; e < 4; ++e)
            out[(size_t)(rowb + e) * 128 + n] = acc[e] + bon;
    }
}

extern "C" void kernel_launch(void* const* d_in, const int* in_sizes, int n_in,
                              void* d_out, int out_size, void* d_ws, size_t ws_size,
                              hipStream_t stream) {
    const float* pair  = (const float*)d_in[0];
    const float* gamma = (const float*)d_in[1];
    const float* beta  = (const float*)d_in[2];
    const float* Wq    = (const float*)d_in[3];
    const float* Wk    = (const float*)d_in[4];
    const float* Wv    = (const float*)d_in[5];
    const float* Wb    = (const float*)d_in[6];
    const float* Wg    = (const float*)d_in[7];
    const float* bg    = (const float*)d_in[8];
    const float* Wo    = (const float*)d_in[9];
    const float* bo    = (const float*)d_in[10];

    unsigned char* ws = (unsigned char*)d_ws;
    size_t off = 0;
    ushort_t* q_bf   = (ushort_t*)(ws + off); off += (size_t)NROW * 128 * 2;
    ushort_t* k_bf   = (ushort_t*)(ws + off); off += (size_t)NROW * 128 * 2;
    ushort_t* v_bf   = (ushort_t*)(ws + off); off += (size_t)NROW * 128 * 2;
    ushort_t* g_bf   = (ushort_t*)(ws + off); off += (size_t)NROW * 128 * 2;
    ushort_t* xh_bf  = (ushort_t*)(ws + off); off += (size_t)NROW * 128 * 2;
    ushort_t* xl_bf  = (ushort_t*)(ws + off); off += (size_t)NROW * 128 * 2;
    float*    biasT  = (float*)(ws + off);    off += (size_t)NH * NROW * 4;
    ushort_t* WtAll  = (ushort_t*)(ws + off); off += 528 * 128 * 2;
    ushort_t* WohT   = (ushort_t*)(ws + off); off += 128 * 128 * 2;
    ushort_t* WolT   = (ushort_t*)(ws + off); off += 128 * 128 * 2;

    prep_kernel<<<49, 256, 0, stream>>>(Wq, Wk, Wv, Wb, Wg, Wo, WtAll, WohT, WolT);
    ln_proj_mfma<<<NROW / 32, 256, 0, stream>>>(pair, gamma, beta, WtAll, bg,
                                                q_bf, k_bf, v_bf, g_bf, biasT);
    attn_mfma<<<L * NH, 512, 0, stream>>>(q_bf, k_bf, v_bf, g_bf, biasT, xh_bf, xl_bf);
    out_proj_mfma<<<NROW / 32, 256, 0, stream>>>(xh_bf, xl_bf, WohT, WolT, bo, (float*)d_out);
}

// Round 11
// 227.432 us; speedup vs baseline: 1.7869x; 1.0092x over previous
//
#include <hip/hip_runtime.h>
#include <math.h>

#define L 256
#define DP 128
#define NH 4
#define DH 32
#define NROW 65536   /* L*L */

typedef unsigned short ushort_t;
typedef __attribute__((ext_vector_type(8))) short short8;
typedef __attribute__((ext_vector_type(4))) float f32x4;
typedef __attribute__((ext_vector_type(4))) unsigned int u32x4;
typedef __attribute__((ext_vector_type(2))) __bf16 bf16x2;

constexpr float SCALING = 0.17677669529663687f;  /* 1/sqrt(32) */
constexpr float LOG2E   = 1.4426950408889634f;

#if __has_builtin(__builtin_amdgcn_exp2f)
#define EXP2F __builtin_amdgcn_exp2f
#else
#define EXP2F exp2f
#endif

static __device__ __forceinline__ unsigned short f2bf(float f) {
    __bf16 h = (__bf16)f;
    return __builtin_bit_cast(unsigned short, h);
}
static __device__ __forceinline__ float bf2f(unsigned short h) {
    unsigned u = ((unsigned)h) << 16;
    return __builtin_bit_cast(float, u);
}
static __device__ __forceinline__ unsigned packbf(float lo, float hi) {
    bf16x2 v = {(__bf16)lo, (__bf16)hi};
    return __builtin_bit_cast(unsigned, v);
}
static __device__ __forceinline__ float bf2f_lo(unsigned u) {
    return __builtin_bit_cast(float, u << 16);
}
static __device__ __forceinline__ float bf2f_hi(unsigned u) {
    return __builtin_bit_cast(float, u & 0xffff0000u);
}

// ---------------- prep: transpose/convert weights ----------------
// WtAll[528][128]: Wq^T*(SCALING*LOG2E), Wk^T, Wv^T, Wg^T, Wb^T, zero-pad.
__global__ __launch_bounds__(256) void prep_kernel(
    const float* __restrict__ Wq, const float* __restrict__ Wk, const float* __restrict__ Wv,
    const float* __restrict__ Wb, const float* __restrict__ Wg, const float* __restrict__ Wo,
    ushort_t* __restrict__ WtAll, ushort_t* __restrict__ WohT, ushort_t* __restrict__ WolT)
{
    int rowi = blockIdx.x * 16 + (threadIdx.x >> 4);
    int d0 = (threadIdx.x & 15) * 8;
    #pragma unroll
    for (int dd = 0; dd < 8; ++dd) {
        int d = d0 + dd;
        if (rowi < 512) {
            int n = rowi & 127;
            float val;
            if (rowi < 128)      val = Wq[d * 128 + n] * (SCALING * LOG2E);
            else if (rowi < 256) val = Wk[d * 128 + n];
            else if (rowi < 384) val = Wv[d * 128 + n];
            else                 val = Wg[d * 128 + n];
            WtAll[rowi * 128 + d] = f2bf(val);
        } else if (rowi < 516) {
            WtAll[rowi * 128 + d] = f2bf(Wb[d * 4 + (rowi - 512)]);
        } else if (rowi < 528) {
            WtAll[rowi * 128 + d] = 0;
        } else if (rowi < 656) {
            int n = rowi - 528;
            WohT[n * 128 + d] = f2bf(Wo[d * 128 + n]);
        } else {
            int n = rowi - 656;
            float wv = Wo[d * 128 + n];
            unsigned short hb = f2bf(wv);
            WolT[n * 128 + d] = f2bf(wv - bf2f(hb));
        }
    }
}

// ---------------- Kernel A: LayerNorm + MFMA projections ----------------
__global__ __launch_bounds__(256) void ln_proj_mfma(
    const float* __restrict__ pair, const float* __restrict__ gamma, const float* __restrict__ beta,
    const ushort_t* __restrict__ WtAll, const float* __restrict__ bgv,
    ushort_t* __restrict__ qo, ushort_t* __restrict__ ko, ushort_t* __restrict__ vo,
    ushort_t* __restrict__ gateo, float* __restrict__ biasT)
{
    __shared__ __align__(16) unsigned char xs[32 * 256];   // [32 rows][128 bf16], swizzled

    const int t = threadIdx.x;
    const int w = t >> 6, lane = t & 63;
    const int c = lane & 15, g = lane >> 4;
    const int base = blockIdx.x * 32;

    // ---- LN (fp32) -> xs bf16 : wave w handles rows w*8 .. w*8+7 ----
    {
        const float* pr = pair + ((size_t)base + w * 8) * DP;
        float e0[8], e1[8];
        #pragma unroll
        for (int r = 0; r < 8; ++r) {
            e0[r] = pr[r * DP + lane];
            e1[r] = pr[r * DP + 64 + lane];
        }
        const float g0 = gamma[lane], g1 = gamma[lane + 64];
        const float b0 = beta[lane],  b1 = beta[lane + 64];
        #pragma unroll
        for (int r = 0; r < 8; ++r) {
            float s = e0[r] + e1[r], ss = e0[r] * e0[r] + e1[r] * e1[r];
            #pragma unroll
            for (int o = 32; o > 0; o >>= 1) { s += __shfl_xor(s, o); ss += __shfl_xor(ss, o); }
            float mu = s * (1.f / DP);
            float rq = rsqrtf(ss * (1.f / DP) - mu * mu + 1e-5f);
            int rl = w * 8 + r;
            unsigned swz = (unsigned)((rl & 7) << 4);
            *(ushort_t*)(xs + (((unsigned)(rl * 256 + 2 * lane)) ^ swz)) = f2bf((e0[r] - mu) * rq * g0 + b0);
            *(ushort_t*)(xs + (((unsigned)(rl * 256 + 2 * (lane + 64))) ^ swz)) = f2bf((e1[r] - mu) * rq * g1 + b1);
        }
    }
    __syncthreads();

    // ---- hoist A-fragments (2 row-groups) ----
    short8 af[2][4];
    #pragma unroll
    for (int rg = 0; rg < 2; ++rg) {
        const int rl = rg * 16 + c;
        const unsigned swz = (unsigned)((rl & 7) << 4);
        #pragma unroll
        for (int kk = 0; kk < 4; ++kk)
            af[rg][kk] = *(const short8*)(xs + (((unsigned)(rl * 256 + kk * 64 + g * 16)) ^ swz));
    }

    // ---- GEMM: wave w owns n-tiles {w, w+4, ..., w+28}; wave 3 also tile 32 ----
    const int mtot = (w == 3) ? 9 : 8;
    for (int m = 0; m < mtot; ++m) {
        const int nt = (m < 8) ? (w + 4 * m) : 32;
        const ushort_t* wbp = WtAll + (size_t)(nt * 16 + c) * 128 + 8 * g;
        short8 bw[4];
        #pragma unroll
        for (int kk = 0; kk < 4; ++kk) bw[kk] = *(const short8*)(wbp + kk * 32);

        const int n = nt * 16 + c;
        #pragma unroll
        for (int rg = 0; rg < 2; ++rg) {
            f32x4 acc = {0.f, 0.f, 0.f, 0.f};
            #pragma unroll
            for (int kk = 0; kk < 4; ++kk)
                acc = __builtin_amdgcn_mfma_f32_16x16x32_bf16(af[rg][kk], bw[kk], acc, 0, 0, 0);

            const int rowb = base + rg * 16 + 4 * g;
            if (nt < 8) {
                #pragma unroll
                for (int e = 0; e < 4; ++e) qo[(size_t)(rowb + e) * 128 + n] = f2bf(acc[e]);
            } else if (nt < 16) {
                #pragma unroll
                for (int e = 0; e < 4; ++e) ko[(size_t)(rowb + e) * 128 + (n - 128)] = f2bf(acc[e]);
            } else if (nt < 24) {
                #pragma unroll
                for (int e = 0; e < 4; ++e) vo[(size_t)(rowb + e) * 128 + (n - 256)] = f2bf(acc[e]);
            } else if (nt < 32) {
                float bgn = bgv[n - 384];
                #pragma unroll
                for (int e = 0; e < 4; ++e)
                    gateo[(size_t)(rowb + e) * 128 + (n - 384)] =
                        f2bf(1.f / (1.f + __expf(-(acc[e] + bgn))));
            } else {
                if (c < 4) {
                    // bias pre-scaled by LOG2E for the attn exp2 path
                    #pragma unroll
                    for (int e = 0; e < 4; ++e)
                        biasT[(size_t)c * NROW + rowb + e] = acc[e] * LOG2E;
                }
            }
        }
    }
}

// ---------------- Kernel B: swapped-operand MFMA attention + gate fusion ----------------
// 512 threads (8 waves x 32 j-rows). S^T = mfma(K, Q, bias_frag) (bias in C);
// exp2 (log2e pre-folded); P^T packed via v_cvt_pk into PV B-operand; O^T = V^T P^T.
__global__ __launch_bounds__(512) void attn_mfma(
    const ushort_t* __restrict__ qbf, const ushort_t* __restrict__ kbf, const ushort_t* __restrict__ vbf,
    const ushort_t* __restrict__ gbf, const float* __restrict__ biasT,
    ushort_t* __restrict__ xh, ushort_t* __restrict__ xl)
{
    __shared__ __align__(16) unsigned char Kb[256 * 80];     // [256 k][32 bf16], stride 80B (bank-spread)
    __shared__ __align__(16) unsigned char Vt[32 * 512];     // [32 d][256 bf16 k-perm], XOR swizzled

    const int h = blockIdx.x & 3, i = blockIdx.x >> 2;
    const int t = threadIdx.x, w = t >> 6, lane = t & 63;
    const int c = lane & 15, g = lane >> 4;

    // ---- Q fragments first (global latency overlaps staging) ----
    const int j0 = w * 32;
    short8 qf[2];
    {
        const ushort_t* qg = qbf + (size_t)(i * 256 + j0) * 128 + h * 32;
        #pragma unroll
        for (int jt = 0; jt < 2; ++jt)
            qf[jt] = *(const short8*)(qg + (size_t)(jt * 16 + c) * 128 + 8 * g);
    }

    // ---- stage K (16B loads, row stride 80B) ----
    {
        const ushort_t* kg = kbf + (size_t)(i * 256) * 128 + h * 32;
        #pragma unroll
        for (int it = 0; it < 2; ++it) {
            int idx = it * 512 + t;          // 0..1023 16B-units
            int kr = idx >> 2, dp4 = idx & 3;
            *(u32x4*)(Kb + kr * 80 + dp4 * 16) = *(const u32x4*)(kg + (size_t)kr * 128 + dp4 * 8);
        }
    }
    // ---- stage V transposed, k-permuted: pos p=g*8+q holds k=(q<4)?4g+q:16+4g+(q-4) ----
    {
        const ushort_t* vg = vbf + (size_t)(i * 256) * 128 + h * 32;
        #pragma unroll
        for (int it = 0; it < 2; ++it) {
            int idx = it * 512 + t;
            int kp = idx >> 3, dp = idx & 7;
            int kt = kp >> 4, cc = kp & 15;
            int a = cc & 3, gg = cc >> 2;
            int k1 = (a < 2) ? (4 * gg + 2 * a) : (12 + 4 * gg + 2 * a);
            int r0 = kt * 32 + k1;
            uint2 va = *(const uint2*)(vg + (size_t)r0 * 128 + dp * 4);
            uint2 vb = *(const uint2*)(vg + (size_t)(r0 + 1) * 128 + dp * 4);
            unsigned av[4] = { va.x & 0xffffu, va.x >> 16, va.y & 0xffffu, va.y >> 16 };
            unsigned bv[4] = { vb.x & 0xffffu, vb.x >> 16, vb.y & 0xffffu, vb.y >> 16 };
            int kcolb = kt * 64 + 4 * cc;
            #pragma unroll
            for (int dd = 0; dd < 4; ++dd) {
                int d = 4 * dp + dd;
                unsigned pk = (bv[dd] << 16) | av[dd];
                *(unsigned*)(Vt + (((unsigned)(d * 512 + kcolb)) ^ ((unsigned)((d & 7) << 4)))) = pk;
            }
        }
    }
    __syncthreads();

    const float* biasH = biasT + (size_t)h * NROW;

    f32x4 O[2][2];
    float rsum[2] = {0.f, 0.f};
    #pragma unroll
    for (int jt = 0; jt < 2; ++jt) {
        O[jt][0] = (f32x4){0.f, 0.f, 0.f, 0.f};
        O[jt][1] = (f32x4){0.f, 0.f, 0.f, 0.f};
    }

    for (int kt = 0; kt < 8; ++kt) {
        short8 kf[2];
        #pragma unroll
        for (int ks = 0; ks < 2; ++ks)
            kf[ks] = *(const short8*)(Kb + (kt * 32 + ks * 16 + c) * 80 + g * 16);
        short8 vb0 = *(const short8*)(Vt + (((unsigned)(c * 512 + kt * 64 + g * 16)) ^ ((unsigned)((c & 7) << 4))));
        short8 vb1 = *(const short8*)(Vt + (((unsigned)((16 + c) * 512 + kt * 64 + g * 16)) ^ ((unsigned)(((16 + c) & 7) << 4))));

        #pragma unroll
        for (int jt = 0; jt < 2; ++jt) {
            const int jrow = j0 + jt * 16 + c;
            const f32x4 b0 = *(const f32x4*)(biasH + (size_t)jrow * 256 + kt * 32 + 4 * g);
            const f32x4 b1 = *(const f32x4*)(biasH + (size_t)jrow * 256 + kt * 32 + 16 + 4 * g);
            // S^T tiles with bias as C-operand: row k_local = ks*16+4g+e, col j = c
            f32x4 s0 = __builtin_amdgcn_mfma_f32_16x16x32_bf16(kf[0], qf[jt], b0, 0, 0, 0);
            f32x4 s1 = __builtin_amdgcn_mfma_f32_16x16x32_bf16(kf[1], qf[jt], b1, 0, 0, 0);
            #pragma unroll
            for (int e = 0; e < 4; ++e) {
                s0[e] = EXP2F(s0[e]);
                s1[e] = EXP2F(s1[e]);
            }
            rsum[jt] += ((s0[0] + s0[1]) + (s0[2] + s0[3])) + ((s1[0] + s1[1]) + (s1[2] + s1[3]));
            u32x4 pk;
            pk[0] = packbf(s0[0], s0[1]);
            pk[1] = packbf(s0[2], s0[3]);
            pk[2] = packbf(s1[0], s1[1]);
            pk[3] = packbf(s1[2], s1[3]);
            short8 pa = __builtin_bit_cast(short8, pk);
            O[jt][0] = __builtin_amdgcn_mfma_f32_16x16x32_bf16(vb0, pa, O[jt][0], 0, 0, 0);
            O[jt][1] = __builtin_amdgcn_mfma_f32_16x16x32_bf16(vb1, pa, O[jt][1], 0, 0, 0);
        }
    }

    // rowsum over g-groups
    #pragma unroll
    for (int jt = 0; jt < 2; ++jt) {
        float v = rsum[jt];
        v += __shfl_xor(v, 16);
        v += __shfl_xor(v, 32);
        rsum[jt] = 1.f / v;
    }
    // epilogue: x = gate .* (O*inv), hi/lo bf16 via cvt_pk, store
    const ushort_t* gB = gbf + (size_t)(i * 256 + j0) * 128 + h * 32;
    ushort_t* xhB = xh + (size_t)(i * 256 + j0) * 128 + h * 32;
    ushort_t* xlB = xl + (size_t)(i * 256 + j0) * 128 + h * 32;
    #pragma unroll
    for (int jt = 0; jt < 2; ++jt) {
        const float inv = rsum[jt];
        #pragma unroll
        for (int dt = 0; dt < 2; ++dt) {
            const int off = (jt * 16 + c) * 128 + dt * 16 + 4 * g;
            uint2 gv = *(const uint2*)(gB + off);
            float x0 = bf2f_lo(gv.x) * O[jt][dt][0] * inv;
            float x1 = bf2f_hi(gv.x) * O[jt][dt][1] * inv;
            float x2 = bf2f_lo(gv.y) * O[jt][dt][2] * inv;
            float x3 = bf2f_hi(gv.y) * O[jt][dt][3] * inv;
            unsigned h01 = packbf(x0, x1), h23 = packbf(x2, x3);
            float r0 = x0 - bf2f_lo(h01), r1 = x1 - bf2f_hi(h01);
            float r2 = x2 - bf2f_lo(h23), r3 = x3 - bf2f_hi(h23);
            uint2 hv = { h01, h23 };
            uint2 lv = { packbf(r0, r1), packbf(r2, r3) };
            *(uint2*)(xhB + off) = hv;
            *(uint2*)(xlB + off) = lv;
        }
    }
}

// ---------------- Kernel C: out = x @ Wo + bo, x = xh+xl bf16 pair ----------------
// grid 2048: block = (64 rows, 4 n-tiles).
__global__ __launch_bounds__(256) void out_proj_mfma(
    const ushort_t* __restrict__ xh, const ushort_t* __restrict__ xl,
    const ushort_t* __restrict__ WohT, const ushort_t* __restrict__ WolT,
    const float* __restrict__ bo, float* __restrict__ out)
{
    const int t = threadIdx.x;
    const int w = t >> 6, lane = t & 63;
    const int c = lane & 15, g = lane >> 4;
    const int base = (blockIdx.x >> 1) * 64;
    const int nh = blockIdx.x & 1;

    const size_t arow = (size_t)(base + w * 16 + c) * 128;
    short8 ah[4], al[4];
    #pragma unroll
    for (int kk = 0; kk < 4; ++kk) {
        ah[kk] = *(const short8*)(xh + arow + kk * 32 + g * 8);
        al[kk] = *(const short8*)(xl + arow + kk * 32 + g * 8);
    }

    const int rowb = base + w * 16 + 4 * g;
    #pragma unroll
    for (int m = 0; m < 4; ++m) {
        const int nt = nh * 4 + m;
        f32x4 acc = {0.f, 0.f, 0.f, 0.f};
        const ushort_t* wh = WohT + (size_t)(nt * 16 + c) * 128 + 8 * g;
        const ushort_t* wl = WolT + (size_t)(nt * 16 + c) * 128 + 8 * g;
        #pragma unroll
        for (int kk = 0; kk < 4; ++kk) {
            short8 bh = *(const short8*)(wh + kk * 32);
            short8 bl = *(const short8*)(wl + kk * 32);
            acc = __builtin_amdgcn_mfma_f32_16x16x32_bf16(ah[kk], bh, acc, 0, 0, 0);
            acc = __builtin_amdgcn_mfma_f32_16x16x32_bf16(ah[kk], bl, acc, 0, 0, 0);
            acc = __builtin_amdgcn_mfma_f32_16x16x32_bf16(al[kk], bh, acc, 0, 0, 0);
        }
        int n = nt * 16 + c;
        float bon = bo[n];
        #pragma unroll
        for (int e = 0; e < 4; ++e)
            out[(size_t)(rowb + e) * 128 + n] = acc[e] + bon;
    }
}

extern "C" void kernel_launch(void* const* d_in, const int* in_sizes, int n_in,
                              void* d_out, int out_size, void* d_ws, size_t ws_size,
                              hipStream_t stream) {
    const float* pair  = (const float*)d_in[0];
    const float* gamma = (const float*)d_in[1];
    const float* beta  = (const float*)d_in[2];
    const float* Wq    = (const float*)d_in[3];
    const float* Wk    = (const float*)d_in[4];
    const float* Wv    = (const float*)d_in[5];
    const float* Wb    = (const float*)d_in[6];
    const float* Wg    = (const float*)d_in[7];
    const float* bg    = (const float*)d_in[8];
    const float* Wo    = (const float*)d_in[9];
    const float* bo    = (const float*)d_in[10];

    unsigned char* ws = (unsigned char*)d_ws;
    size_t off = 0;
    ushort_t* q_bf   = (ushort_t*)(ws + off); off += (size_t)NROW * 128 * 2;
    ushort_t* k_bf   = (ushort_t*)(ws + off); off += (size_t)NROW * 128 * 2;
    ushort_t* v_bf   = (ushort_t*)(ws + off); off += (size_t)NROW * 128 * 2;
    ushort_t* g_bf   = (ushort_t*)(ws + off); off += (size_t)NROW * 128 * 2;
    ushort_t* xh_bf  = (ushort_t*)(ws + off); off += (size_t)NROW * 128 * 2;
    ushort_t* xl_bf  = (ushort_t*)(ws + off); off += (size_t)NROW * 128 * 2;
    float*    biasT  = (float*)(ws + off);    off += (size_t)NH * NROW * 4;
    ushort_t* WtAll  = (ushort_t*)(ws + off); off += 528 * 128 * 2;
    ushort_t* WohT   = (ushort_t*)(ws + off); off += 128 * 128 * 2;
    ushort_t* WolT   = (ushort_t*)(ws + off); off += 128 * 128 * 2;

    prep_kernel<<<49, 256, 0, stream>>>(Wq, Wk, Wv, Wb, Wg, Wo, WtAll, WohT, WolT);
    ln_proj_mfma<<<NROW / 32, 256, 0, stream>>>(pair, gamma, beta, WtAll, bg,
                                                q_bf, k_bf, v_bf, g_bf, biasT);
    attn_mfma<<<L * NH, 512, 0, stream>>>(q_bf, k_bf, v_bf, g_bf, biasT, xh_bf, xl_bf);
    out_proj_mfma<<<NROW / 32, 256, 0, stream>>>(xh_bf, xl_bf, WohT, WolT, bo, (float*)d_out);
}